// Round 1
// baseline (95.023 us; speedup 1.0000x reference)
//
#include <hip/hip_runtime.h>
#include <stdint.h>

using short8 = __attribute__((ext_vector_type(8))) short;
using f32x4  = __attribute__((ext_vector_type(4))) float;

#define OUT_F 11008
#define IN_F  4096
#define TOK   64
#define WPR   (IN_F/8)        // 512 packed words per weight row
#define BN    128
#define KSPLIT 4
#define KQ    (IN_F/KSPLIT)   // 1024
#define BK    256             // k-chunk staged in LDS
#define NCH   (KQ/BK)         // 4
#define NBLK  (OUT_F/BN)      // 86

__device__ __forceinline__ unsigned short f2bf(float f) {
    uint32_t u = __float_as_uint(f);
    u += 0x7FFFu + ((u >> 16) & 1u);   // round-to-nearest-even
    return (unsigned short)(u >> 16);
}

// x fp32 -> bf16 into workspace, vectorized (8 elems/thread)
__global__ __launch_bounds__(256) void cvt_kernel(const float* __restrict__ x,
                                                  unsigned short* __restrict__ xb) {
    int t = blockIdx.x * 256 + threadIdx.x;
    const float4* xv = (const float4*)x;
    float4 a = xv[2*t], b = xv[2*t+1];
    union { short8 v; unsigned short u[8]; } o;
    o.u[0]=f2bf(a.x); o.u[1]=f2bf(a.y); o.u[2]=f2bf(a.z); o.u[3]=f2bf(a.w);
    o.u[4]=f2bf(b.x); o.u[5]=f2bf(b.y); o.u[6]=f2bf(b.z); o.u[7]=f2bf(b.w);
    ((short8*)xb)[t] = o.v;
}

// 8 packed sign bits (MSB-first: k=j uses bit 7-j) -> 8 bf16 in {-1,+1}
__device__ __forceinline__ short8 unpack_w(uint32_t w) {
    union { short8 v; uint32_t u[4]; } r;
#pragma unroll
    for (int p = 0; p < 4; ++p) {
        uint32_t lo = (w << (8  + 2*p)) & 0x8000u;      // bit for k=2p   -> bit15
        uint32_t hi = (w << (25 + 2*p)) & 0x80000000u;  // bit for k=2p+1 -> bit31
        r.u[p] = 0xBF80BF80u ^ lo ^ hi;                 // bit=1 -> +1 (0x3F80), 0 -> -1
    }
    return r.v;
}

__global__ __launch_bounds__(256) void gemm_kernel(const unsigned short* __restrict__ xb,
                                                   const uint32_t* __restrict__ bp,
                                                   const float* __restrict__ scale,
                                                   float* __restrict__ out) {
    // x tile [64 rows][256 k] bf16, XOR-swizzled: LDS[row][col] = x[row][col ^ ((row&7)<<4)]
    __shared__ __align__(128) unsigned char xs[TOK * BK * 2];   // 32 KB

    const int bid  = blockIdx.x;
    const int nblk = bid % NBLK;
    const int q    = bid / NBLK;        // k-split index 0..3
    const int n0   = nblk * BN;
    const int tid  = threadIdx.x;
    const int wv   = tid >> 6;
    const int lane = tid & 63;
    const int l15  = lane & 15;
    const int lg   = lane >> 4;

    f32x4 acc[2][4];
#pragma unroll
    for (int nf = 0; nf < 2; ++nf)
#pragma unroll
        for (int mt = 0; mt < 4; ++mt) acc[nf][mt] = (f32x4){0.f, 0.f, 0.f, 0.f};

    // each lane's B-fragment source: one bp word per k-step (8 bits = 8 k)
    const int nr0 = n0 + wv*32 + l15;
    const uint32_t* bpr0 = bp + (size_t)nr0 * WPR + q*(KQ/8) + lg;
    const uint32_t* bpr1 = bpr0 + 16*WPR;

    // staging geometry: iter i covers rows i*8 + tid/32, 16B per lane,
    // global source pre-swizzled so linear global_load_lds dest yields swizzled LDS
    const int srow   = tid >> 5;                                  // 0..7
    const int scolsw = ((tid & 31) * 16) ^ ((srow & 7) << 4);
    const unsigned char* xbb = (const unsigned char*)xb;

    for (int c = 0; c < NCH; ++c) {
        __syncthreads();                       // previous chunk's reads done
        const int kcb = (q*KQ + c*BK) * 2;     // byte offset within x row
#pragma unroll
        for (int i = 0; i < 8; ++i) {
            int row = i*8 + srow;
            const void* g = xbb + row*(IN_F*2) + kcb + scolsw;
            void* l = (void*)(xs + i*4096 + wv*1024);
            __builtin_amdgcn_global_load_lds(
                (const __attribute__((address_space(1))) void*)g,
                (__attribute__((address_space(3))) void*)l,
                16, 0, 0);
        }
        __syncthreads();                       // drains vmcnt before barrier

        const int wbase = c*(BK/8);
#pragma unroll
        for (int kk = 0; kk < 8; ++kk) {
            uint32_t w0 = bpr0[wbase + kk*4];
            uint32_t w1 = bpr1[wbase + kk*4];
            short8 b0 = unpack_w(w0);
            short8 b1 = unpack_w(w1);
#pragma unroll
            for (int mt = 0; mt < 4; ++mt) {
                int row = mt*16 + l15;
                int ba  = (row*512 + kk*64 + lg*16) ^ ((row & 7) << 4);
                short8 af = *(const short8*)(xs + ba);   // ds_read_b128, conflict-free
                acc[0][mt] = __builtin_amdgcn_mfma_f32_16x16x32_bf16(af, b0, acc[0][mt], 0, 0, 0);
                acc[1][mt] = __builtin_amdgcn_mfma_f32_16x16x32_bf16(af, b1, acc[1][mt], 0, 0, 0);
            }
        }
    }

    // epilogue: scale + k-split accumulate via fp32 atomics
    float sc0 = scale[n0 + wv*32 + l15];
    float sc1 = scale[n0 + wv*32 + 16 + l15];
#pragma unroll
    for (int mt = 0; mt < 4; ++mt)
#pragma unroll
        for (int j = 0; j < 4; ++j) {
            int m = mt*16 + lg*4 + j;              // token index (D: row=(l>>4)*4+reg)
            atomicAdd(out + (size_t)m*OUT_F + n0 + wv*32 + l15,      acc[0][mt][j]*sc0);
            atomicAdd(out + (size_t)m*OUT_F + n0 + wv*32 + 16 + l15, acc[1][mt][j]*sc1);
        }
}

extern "C" void kernel_launch(void* const* d_in, const int* in_sizes, int n_in,
                              void* d_out, int out_size, void* d_ws, size_t ws_size,
                              hipStream_t stream) {
    const float*    x     = (const float*)d_in[0];
    const uint32_t* bp    = (const uint32_t*)d_in[1];
    const float*    scale = (const float*)d_in[2];
    float* out = (float*)d_out;
    unsigned short* xb = (unsigned short*)d_ws;    // 64*4096 bf16 = 512 KB

    hipMemsetAsync(d_out, 0, (size_t)TOK * OUT_F * sizeof(float), stream);
    cvt_kernel<<<dim3((TOK*IN_F)/(256*8)), dim3(256), 0, stream>>>(x, xb);
    gemm_kernel<<<dim3(NBLK*KSPLIT), dim3(256), 0, stream>>>(xb, bp, scale, out);
}